// Round 5
// baseline (220.565 us; speedup 1.0000x reference)
//
#include <hip/hip_runtime.h>
#include <hip/hip_bf16.h>
#include <math.h>

#define BATCH 8
#define SEQ   4096
#define DIM   64
#define LQ    2744            // int((1-0.33)*4096)
#define QPB   128             // queries per attn block
#define NQB   22              // ceil(2744/128)
#define QPAD  2816            // NQB*QPB
#define KS    8               // key splits (512 keys per block)
#define L2E   1.4426950408889634f
#define QSC   0.1803368801111204f   // 0.125 * log2(e), folded into Qh

typedef _Float16 half8 __attribute__((ext_vector_type(8)));
typedef short    bs8   __attribute__((ext_vector_type(8)));
typedef float    fx16  __attribute__((ext_vector_type(16)));
typedef unsigned short ushort_t;

union UH { uint4 u4; half8 h; };
union UB { unsigned u[4]; uint4 u4; bs8 s; };

// RNE bf16 pack, 3 int ops per value (p >= 0, never NaN/Inf here)
__device__ __forceinline__ unsigned pack_bf16(float a, float b) {
    unsigned ua = __float_as_uint(a), ub = __float_as_uint(b);
    ua += 0x7FFFu + ((ua >> 16) & 1u);
    ub += 0x7FFFu + ((ub >> 16) & 1u);
    return (ua >> 16) | (ub & 0xFFFF0000u);
}

// ---------------- sortable-uint mapping ----------------
__device__ __forceinline__ unsigned f2sort(float f) {
    unsigned u = __float_as_uint(f);
    return (u & 0x80000000u) ? ~u : (u | 0x80000000u);
}
__device__ __forceinline__ float sort2f(unsigned u) {
    return __uint_as_float((u & 0x80000000u) ? (u & 0x7FFFFFFFu) : ~u);
}

// ---------------- radix select: k-th largest of 4096 (NT threads) --------
// res[0] = key of k-th largest; res[1] = #elems equal to key in the top-k.
template <int NT>
__device__ void radix_select_4096(const unsigned* u, int k, unsigned* hist,
                                  unsigned* scan, unsigned* res) {
    const int t = threadIdx.x;
    if (t == 0) { res[0] = 0u; res[1] = (unsigned)k; }
    for (int pass = 3; pass >= 0; --pass) {
        const int shift = pass * 8;
        if (t < 256) hist[t] = 0u;
        __syncthreads();
        const unsigned pref  = res[0];
        const unsigned kk    = res[1];
        const unsigned hmask = (pass == 3) ? 0u : (0xFFFFFFFFu << (shift + 8));
        for (int i = t; i < 4096; i += NT) {
            unsigned ui = u[i];
            if ((ui & hmask) == pref) atomicAdd(&hist[(ui >> shift) & 255u], 1u);
        }
        __syncthreads();
        unsigned h = 0u, s = 0u;
        if (t < 256) { h = hist[t]; s = h; scan[t] = s; }
        __syncthreads();
#pragma unroll
        for (int ofs = 1; ofs < 256; ofs <<= 1) {
            unsigned add = (t < 256 && t + ofs < 256) ? scan[t + ofs] : 0u;
            __syncthreads();
            if (t < 256) { s += add; scan[t] = s; }
            __syncthreads();
        }
        if (t < 256 && s >= kk && (s - h) < kk) {   // unique threshold bin
            res[0] = pref | ((unsigned)t << shift);
            res[1] = kk - (s - h);
        }
        __syncthreads();
    }
}

// ---------------- K1: projections -------------------
__global__ __launch_bounds__(256) void proj_kernel(
    const float* __restrict__ x,  const float* __restrict__ Wq,
    const float* __restrict__ Wk, const float* __restrict__ Wv,
    float* __restrict__ Q, float* __restrict__ Kt,
    _Float16* __restrict__ Qh, _Float16* __restrict__ Kh,
    ushort_t* __restrict__ Vt, float* __restrict__ pmean) {
    const int rt = blockIdx.x, b = blockIdx.y, t = threadIdx.x;
    __shared__ float4 xs4[64 * 17];
    __shared__ float  red[4][64];
    {
        const float4* xg = (const float4*)(x + ((size_t)b * SEQ + rt * 64) * DIM);
        for (int i = 0; i < 4; ++i) {
            int s = t + 256 * i;
            xs4[(s >> 4) * 17 + (s & 15)] = xg[s];
        }
    }
    __syncthreads();
    const int ch = t & 63, rg = t >> 6;
    float accq[16], acck[16], accv[16];
#pragma unroll
    for (int i = 0; i < 16; ++i) { accq[i] = 0.f; acck[i] = 0.f; accv[i] = 0.f; }
    for (int dc = 0; dc < 4; ++dc) {
        float wq[16], wk[16], wv[16];
#pragma unroll
        for (int dd = 0; dd < 16; ++dd) {
            int d = dc * 16 + dd;
            wq[dd] = Wq[d * 64 + ch]; wk[dd] = Wk[d * 64 + ch]; wv[dd] = Wv[d * 64 + ch];
        }
        for (int r = 0; r < 16; ++r) {
            const int row = rg * 16 + r;
            const float4* xr = &xs4[row * 17 + dc * 4];
            float xv[16];
            float4 a0 = xr[0], a1 = xr[1], a2 = xr[2], a3 = xr[3];
            xv[0]=a0.x; xv[1]=a0.y; xv[2]=a0.z; xv[3]=a0.w;
            xv[4]=a1.x; xv[5]=a1.y; xv[6]=a1.z; xv[7]=a1.w;
            xv[8]=a2.x; xv[9]=a2.y; xv[10]=a2.z; xv[11]=a2.w;
            xv[12]=a3.x; xv[13]=a3.y; xv[14]=a3.z; xv[15]=a3.w;
#pragma unroll
            for (int dd = 0; dd < 16; ++dd) {
                accq[r] = fmaf(xv[dd], wq[dd], accq[r]);
                acck[r] = fmaf(xv[dd], wk[dd], acck[r]);
                accv[r] = fmaf(xv[dd], wv[dd], accv[r]);
            }
        }
    }
    const int rowbase = rt * 64 + rg * 16;
    float sv = 0.f;
#pragma unroll
    for (int r = 0; r < 16; ++r) {
        size_t o = ((size_t)b * SEQ + rowbase + r) * DIM + ch;
        Q[o]  = accq[r];
        Qh[o] = (_Float16)(accq[r] * QSC);
        Kh[o] = (_Float16)acck[r];
        sv += accv[r];
    }
    float4* ktp = (float4*)(Kt + ((size_t)b * 64 + ch) * SEQ + rowbase);
    ktp[0] = make_float4(acck[0], acck[1], acck[2], acck[3]);
    ktp[1] = make_float4(acck[4], acck[5], acck[6], acck[7]);
    ktp[2] = make_float4(acck[8], acck[9], acck[10], acck[11]);
    ktp[3] = make_float4(acck[12], acck[13], acck[14], acck[15]);
    // Vt bf16, k-permuted pair order within each 16-group: [0,1,4,5,2,3,6,7]
    {
        unsigned pk[8];
#pragma unroll
        for (int i = 0; i < 8; ++i) {
            __hip_bfloat162 h2 = __float22bfloat162_rn(make_float2(accv[2*i], accv[2*i+1]));
            union { __hip_bfloat162 h; unsigned u; } cv; cv.h = h2;
            pk[i] = cv.u;
        }
        uint4* vp = (uint4*)(Vt + ((size_t)(b * 64 + ch)) * SEQ + rowbase);
        vp[0] = make_uint4(pk[0], pk[1], pk[4], pk[5]);
        vp[1] = make_uint4(pk[2], pk[3], pk[6], pk[7]);
    }
    red[rg][ch] = sv;
    __syncthreads();
    if (rg == 0)
        pmean[((size_t)b * 64 + ch) * 64 + rt] =
            red[0][ch] + red[1][ch] + red[2][ch] + red[3][ch];
}

// ---------------- K2: K_reduce = mean of top-LQ per (b,ch); V-mean agg ---
__global__ __launch_bounds__(1024) void kmean_kernel(const float* __restrict__ Kt,
                                                     const float* __restrict__ pmean,
                                                     float* __restrict__ Kred,
                                                     float* __restrict__ meanfin) {
    __shared__ unsigned u[4096];
    __shared__ unsigned hist[256];
    __shared__ unsigned scan[256];
    __shared__ unsigned res[2];
    __shared__ float rsum[16];
    const int bc = blockIdx.x, t = threadIdx.x;
    if (t < 64) {   // V-mean aggregation: wave 0 sums the 64 partials
        float v = pmean[(size_t)bc * 64 + t];
        for (int m = 1; m < 64; m <<= 1) v += __shfl_xor(v, m, 64);
        if (t == 0) meanfin[bc] = v * (1.0f / (float)SEQ);
    }
    const float4* c4 = (const float4*)(Kt + (size_t)bc * SEQ);
    if (t < 1024) {
        float4 v = c4[t];
        u[t*4+0] = f2sort(v.x); u[t*4+1] = f2sort(v.y);
        u[t*4+2] = f2sort(v.z); u[t*4+3] = f2sort(v.w);
    }
    __syncthreads();
    radix_select_4096<1024>(u, LQ, hist, scan, res);
    const unsigned Tu = res[0];
    const int krem = (int)res[1];
    float loc = 0.f;
    for (int i = t; i < 4096; i += 1024)
        if (u[i] > Tu) loc += sort2f(u[i]);
    for (int msk = 1; msk < 64; msk <<= 1) loc += __shfl_xor(loc, msk, 64);
    if ((t & 63) == 0) rsum[t >> 6] = loc;
    __syncthreads();
    if (t == 0) {
        float s = (float)krem * sort2f(Tu);
        for (int i = 0; i < 16; ++i) s += rsum[i];
        Kred[bc] = s / (float)LQ;
    }
}

// ---------------- K3: fused sqk + per-batch top-LQ selection -------------
__global__ __launch_bounds__(1024) void select_kernel(const float* __restrict__ Q,
                                                      const float* __restrict__ Kred,
                                                      int* __restrict__ sel,
                                                      int* __restrict__ inv) {
    __shared__ unsigned u[4096];
    __shared__ unsigned hist[256];
    __shared__ unsigned scan[256];
    __shared__ unsigned res[2];
    __shared__ float kr[64];
    __shared__ int eq_idx[256];
    __shared__ int cnts[2];
    const int b = blockIdx.x, t = threadIdx.x;
    if (t < 64) kr[t] = Kred[b * 64 + t];
    if (t < 2) cnts[t] = 0;
    int* invb = inv + (size_t)b * SEQ;
    __syncthreads();
    // sqk inline: 4 rows per thread (fp32, same FMA order as before)
    for (int row = t; row < 4096; row += 1024) {
        const float4* q = (const float4*)(Q + ((size_t)b * SEQ + row) * DIM);
        float s = 0.f;
#pragma unroll
        for (int i = 0; i < 16; ++i) {
            float4 v = q[i];
            s = fmaf(v.x, kr[i*4+0], s); s = fmaf(v.y, kr[i*4+1], s);
            s = fmaf(v.z, kr[i*4+2], s); s = fmaf(v.w, kr[i*4+3], s);
        }
        u[row] = f2sort(s);
        invb[row] = -1;
    }
    __syncthreads();
    radix_select_4096<1024>(u, LQ, hist, scan, res);
    const unsigned Tu = res[0];
    const int krem = (int)res[1];
    int* selb = sel + b * QPAD;
    for (int i = t; i < 4096; i += 1024) {
        unsigned ui = u[i];
        if (ui > Tu) {
            int p = atomicAdd(&cnts[0], 1);
            selb[p] = i;
            invb[i] = p;
        } else if (ui == Tu) {
            int p = atomicAdd(&cnts[1], 1);
            if (p < 256) eq_idx[p] = i;
        }
    }
    __syncthreads();
    if (t == 0) {
        int ng = cnts[0];
        int ne = cnts[1] < 256 ? cnts[1] : 256;
        for (int i = 1; i < ne; ++i) {          // ties ~unique floats: ne≈1
            int v = eq_idx[i], j = i - 1;
            while (j >= 0 && eq_idx[j] > v) { eq_idx[j+1] = eq_idx[j]; --j; }
            eq_idx[j+1] = v;
        }
        for (int j = 0; j < krem; ++j) {
            selb[ng + j] = eq_idx[j];
            invb[eq_idx[j]] = ng + j;
        }
    }
    __syncthreads();
    if (t < QPAD - LQ) selb[LQ + t] = selb[LQ - 1];   // pad (parallel)
}

// ---------------- K4: MFMA flash attention (no-max online softmax) -------
// KS=8 key splits (grid 1408, ~5.5 blocks/CU) to hide the per-tile
// MFMA->exp->MFMA chain with wave-level parallelism. Partials are plain
// sums, so key-split merge = global fp32 atomicAdd into zeroed pout/pl.
__global__ __launch_bounds__(256, 3) void attn_kernel(
    const ushort_t* __restrict__ Qh, const ushort_t* __restrict__ Kh,
    const ushort_t* __restrict__ Vt, const int* __restrict__ sel,
    float* __restrict__ pl, float* __restrict__ pout) {
    const int qt = blockIdx.x, ks = blockIdx.y, b = blockIdx.z;
    const int t = threadIdx.x, w = t >> 6, lane = t & 63;
    const int col = lane & 31, h = lane >> 5;

    __shared__ ushort_t Ktile[2][32 * 64];
    __shared__ ushort_t Vtile[2][32 * 64];

    // persistent Q fragments (B-operand: lane holds q=col, d=16m+8h+j)
    half8 qf[4];
    {
        const int q = qt * QPB + w * 32 + col;
        const int row = sel[b * QPAD + q];
        const uint4* qg = (const uint4*)(Qh + ((size_t)b * SEQ + row) * DIM);
#pragma unroll
        for (int m = 0; m < 4; ++m) { UH u; u.u4 = qg[2 * m + h]; qf[m] = u.h; }
    }

    // loop-invariant swizzled LDS offsets (ushort elements)
    int koff[4], voff[4];
#pragma unroll
    for (int m = 0; m < 4; ++m)
        koff[m] = col * 64 + 8 * ((2 * m + h) ^ (col & 7));
#pragma unroll
    for (int i = 0; i < 4; ++i)
        voff[i] = col * 64 + 8 * ((i * 2 + h) ^ (col & 7));

    fx16 O0, O1;
#pragma unroll
    for (int r = 0; r < 16; ++r) { O0[r] = 0.f; O1[r] = 0.f; }
    float l = 0.f;

    const int srow = t >> 3, sgr = t & 7;
    const int lg = sgr ^ (srow & 7);
    const int vD = lg >> 2, vc = (lg >> 1) & 1, vh = lg & 1;
    const size_t kgbase = ((size_t)b * SEQ + ks * 512 + srow) * DIM + 8 * lg;
    const size_t vgbase = ((size_t)(b * DIM + srow + 32 * vD)) * SEQ
                          + ks * 512 + vc * 16 + vh * 8;

    uint4 kreg = *(const uint4*)(Kh + kgbase);
    uint4 vreg = *(const uint4*)(Vt + vgbase);

    for (int tile = 0; tile < 16; ++tile) {
        const int buf = tile & 1;
        *(uint4*)&Ktile[buf][srow * 64 + sgr * 8] = kreg;
        *(uint4*)&Vtile[buf][srow * 64 + sgr * 8] = vreg;
        __syncthreads();
        if (tile < 15) {   // prefetch next tile during compute
            kreg = *(const uint4*)(Kh + kgbase + (size_t)(tile + 1) * 32 * DIM);
            vreg = *(const uint4*)(Vt + vgbase + (size_t)(tile + 1) * 32);
        }
        // S^T = K * Q^T  (f16 MFMA); Qh pre-scaled by 0.125*log2e
        fx16 S;
#pragma unroll
        for (int r = 0; r < 16; ++r) S[r] = 0.f;
#pragma unroll
        for (int m = 0; m < 4; ++m) {
            UH kf;
            kf.u4 = *(const uint4*)&Ktile[buf][koff[m]];
            S = __builtin_amdgcn_mfma_f32_32x32x16_f16(kf.h, qf[m], S, 0, 0, 0);
        }
        // softmax numerators (raw v_exp_f32; scores bounded « 128)
        float p[16];
#pragma unroll
        for (int r = 0; r < 16; ++r) p[r] = __builtin_amdgcn_exp2f(S[r]);
#pragma unroll
        for (int r = 0; r < 16; ++r) l += p[r];
        UB A0, A1;
#pragma unroll
        for (int v = 0; v < 4; ++v) {
            A0.u[v] = pack_bf16(p[2 * v],     p[2 * v + 1]);
            A1.u[v] = pack_bf16(p[8 + 2 * v], p[8 + 2 * v + 1]);
        }
        // O += P * V  (bf16 MFMA)
#pragma unroll
        for (int D = 0; D < 2; ++D) {
            fx16& O = D ? O1 : O0;
#pragma unroll
            for (int c = 0; c < 2; ++c) {
                UB vf;
                vf.u4 = *(const uint4*)&Vtile[buf][voff[D * 2 + c]];
                O = __builtin_amdgcn_mfma_f32_32x32x16_bf16(c ? A1.s : A0.s, vf.s, O, 0, 0, 0);
            }
        }
    }

    l += __shfl_xor(l, 32);   // combine the two k-halves of the column sum

    const int qg0 = qt * QPB + w * 32;
    const size_t base = (size_t)b * QPAD + qg0;
#pragma unroll
    for (int D = 0; D < 2; ++D) {
        const fx16& O = D ? O1 : O0;
#pragma unroll
        for (int r = 0; r < 16; ++r) {
            const int q = (r & 3) + 8 * (r >> 2) + 4 * h;
            atomicAdd(&pout[(base + q) * DIM + D * 32 + col], O[r]);
        }
    }
    if (h == 0) atomicAdd(&pl[base + col], l);
}

// ---------------- K5: normalize+scatter OR mean-fill, one pass -----------
__global__ __launch_bounds__(256) void comb_kernel(
    const float* __restrict__ pl, const float* __restrict__ pout,
    const int* __restrict__ inv, const float* __restrict__ meanfin,
    float* __restrict__ out) {
    const int idx = blockIdx.x * 256 + threadIdx.x;   // over BATCH*SEQ*16
    const int b = idx >> 16;
    const int rc = idx & 65535;
    const int row = rc >> 4, c = rc & 15;
    const int p = inv[b * SEQ + row];
    float4 o;
    if (p >= 0) {
        const size_t s0 = (size_t)b * QPAD + p;
        const float invl = 1.0f / pl[s0];
        float4 a = ((const float4*)(pout + s0 * DIM))[c];
        o = make_float4(a.x * invl, a.y * invl, a.z * invl, a.w * invl);
    } else {
        o = make_float4(meanfin[b * 64 + c * 4 + 0], meanfin[b * 64 + c * 4 + 1],
                        meanfin[b * 64 + c * 4 + 2], meanfin[b * 64 + c * 4 + 3]);
    }
    ((float4*)out)[idx] = o;
}

// ---------------- launcher ----------------
extern "C" void kernel_launch(void* const* d_in, const int* in_sizes, int n_in,
                              void* d_out, int out_size, void* d_ws, size_t ws_size,
                              hipStream_t stream) {
    const float* x  = (const float*)d_in[0];
    const float* Wq = (const float*)d_in[1];
    const float* Wk = (const float*)d_in[2];
    const float* Wv = (const float*)d_in[3];
    float* out = (float*)d_out;
    char* wsb  = (char*)d_ws;

    // workspace layout (bytes), total ~27.4 MB
    float*    Q       = (float*)(wsb);                 //  8,388,608
    _Float16* Qh      = (_Float16*)(wsb + 8388608);    //  4,194,304
    _Float16* Kh      = (_Float16*)(wsb + 12582912);   //  4,194,304
    ushort_t* Vt      = (ushort_t*)(wsb + 16777216);   //  4,194,304
    float*    pmean   = (float*)(wsb + 20971520);      //  131,072
    float*    meanfin = (float*)(wsb + 21102592);      //  2,048
    float*    Kred    = (float*)(wsb + 21104640);      //  2,048
    int*      sel     = (int*)(wsb + 21106688);        //  90,112
    int*      inv     = (int*)(wsb + 21196800);        //  131,072
    // alias region: Kt (8,388,608) until kmean consumes it; then pout+pl
    float*    Kt      = (float*)(wsb + 21327872);
    float*    pout    = (float*)(wsb + 21327872);      //  5,767,168
    float*    pl      = (float*)(wsb + 21327872 + 5767168);  // 90,112

    proj_kernel  <<<dim3(64, 8),          256,  0, stream>>>(x, Wq, Wk, Wv, Q, Kt,
                                                             Qh, Kh, Vt, pmean);
    kmean_kernel <<<512,                  1024, 0, stream>>>(Kt, pmean, Kred, meanfin);
    select_kernel<<<8,                    1024, 0, stream>>>(Q, Kred, sel, inv);
    // Kt dead after kmean; zero the region for the attention atomics.
    hipMemsetAsync(pout, 0, 5767168 + 90112, stream);
    attn_kernel  <<<dim3(NQB, KS, BATCH), 256,  0, stream>>>((const ushort_t*)Qh,
                                                             (const ushort_t*)Kh,
                                                             Vt, sel, pl, pout);
    comb_kernel  <<<2048,                 256,  0, stream>>>(pl, pout, inv, meanfin, out);
}